// Round 15
// baseline (78.629 us; speedup 1.0000x reference)
//
#include <hip/hip_runtime.h>

// Problem constants (B=16, T=2048 fixed by setup_inputs)
constexpr int NB = 16;
constexpr int NT = 2048;
constexpr int KPROP = 2000;
constexpr int CAP = 8192;       // candidate cap
constexpr int TIE_CAP = 2048;
constexpr int INC_HI = 12288;   // phase-1 window: included in [INC_LO, INC_HI]
constexpr int INC_LO = 5000;

// ---------------------------------------------------------------------------
// ws layout (bytes):
//   0      : gMode[16] int   (1 = threshold scatter, 2 = all-candidates)
//   64     : gV32[16]  u32   (exact 32-bit K-th score bit pattern)
//   128    : gNd2[16]  int   (ties at V32 still to keep)
//   192    : gCnt[16]  int   (candidate count)
//   4096   : candFlat[16][8192] u32  (flat = s*2048+e)      512 KB
//   528384 : candBits[16][8192] u32  (score bit pattern)    512 KB
// ---------------------------------------------------------------------------

// Descending scan over nbuck-bucket histogram.  [verified R9-R13]
__device__ void dscan(const unsigned* __restrict__ h, int nbuck, int nd, int tid,
                      int* cs, int* oB, int* oNd) {
    int chunk = nbuck >> 8;
    if (tid < 256) {
        int base = tid * chunk, s2 = 0;
        for (int c = 0; c < chunk; c++) s2 += (int)h[base + c];
        cs[tid] = s2;
    }
    __syncthreads();
    if (tid == 0) {
        int acc = 0, tc = -1;
        for (int t2 = 255; t2 >= 0; t2--) {
            if (acc + cs[t2] >= nd) { tc = t2; break; }
            acc += cs[t2];
        }
        int found = -1;
        if (tc >= 0) {
            for (int c = tc * chunk + chunk - 1; c >= tc * chunk; c--) {
                int cnt = (int)h[c];
                if (acc + cnt >= nd) { found = c; break; }
                acc += cnt;
            }
        }
        *oB = found;
        *oNd = nd - acc;
    }
    __syncthreads();
}

// Exclusive block scan over 512 per-thread ints.  [verified R11-R13]
__device__ int scan512_excl(int x, int tid, volatile int* wsum, int* totOut) {
    int lane = tid & 63, wv = tid >> 6;
    int inc = x;
    #pragma unroll
    for (int d = 1; d < 64; d <<= 1) {
        int y = __shfl_up(inc, d);
        if (lane >= d) inc += y;
    }
    if (lane == 63) wsum[wv] = inc;
    __syncthreads();
    int base = 0, tot = 0;
    for (int w2 = 0; w2 < 8; w2++) {
        int v2 = wsum[w2];
        if (w2 < wv) base += v2;
        tot += v2;
    }
    __syncthreads();
    *totOut = tot;
    return base + (inc - x);
}

// Block-wide int sum; all threads receive the total.  [verified R11-R13]
__device__ int reduce512(int x, int tid, volatile int* wsum) {
    int lane = tid & 63, wv = tid >> 6;
    #pragma unroll
    for (int d = 32; d > 0; d >>= 1) x += __shfl_down(x, d);
    if (lane == 0) wsum[wv] = x;
    __syncthreads();
    int tot = 0;
    for (int w2 = 0; w2 < 8; w2++) tot += wsum[w2];
    __syncthreads();
    return tot;
}

// K1: blocks [16, 2064) zero the 268 MB output. Blocks [0,16): one batch each:
// select -> counting-sort e by value (row's included set = PREFIX of evVs) ->
// phase-1 bisect t40 (bucket-prefix oracle, window [5000,12288]) -> compact
// ACTIVE rows (C>0) -> pass A: store all valid-included pairs + value-linear
// histogram + exact cert #(prod>=t40) -> (rare) overflow bucket-cut pass B ->
// 3-level bit refinement -> persist. Exact full-scan fallback if cert fails.
__global__ __launch_bounds__(512) void k_main(
        const float* __restrict__ start, const float* __restrict__ end,
        float4* __restrict__ out4,
        int* __restrict__ gMode, unsigned* __restrict__ gV32,
        int* __restrict__ gNd2, int* __restrict__ gCnt,
        unsigned* __restrict__ candFlat, unsigned* __restrict__ candBits) {
    int blk = blockIdx.x, tid = threadIdx.x;
    if (blk >= NB) {                     // ---- fill path: 131072 B per block ----
        float4 z = make_float4(0.f, 0.f, 0.f, 0.f);
        size_t base = (size_t)(blk - NB) * 8192 + tid;
        #pragma unroll
        for (int it = 0; it < 16; it++) out4[base + (size_t)it * 512] = z;
        return;
    }
    int b = blk;
    size_t bc = (size_t)b * CAP;

    __shared__ short lsI[NT];  __shared__ float lsV[NT];    // s anchors, idx order
    __shared__ short leI[NT];  __shared__ float evV[NT];    // e anchors, idx order
    __shared__ float evVs[NT]; __shared__ short evIs[NT];   // e, bucket-desc sorted
    __shared__ short actI[NT]; __shared__ short actC[NT];   // active rows + counts
    __shared__ unsigned Pmut[2048];      // bucket hist -> scatter ctr -> prod hist
    __shared__ short PE[2051];           // exclusive prefix over desc-bucket key
    __shared__ int   sc512[512];
    __shared__ float redS[512];
    __shared__ int   red8[8];
    __shared__ int   cs[256];
    __shared__ float sMaxA[2];
    __shared__ int   sN[2];
    __shared__ int   scnt, sB, sNd;

    int lane = tid & 63, wv = tid >> 6;
    int (*sc2)[256] = (int(*)[256])sc512;

    // ---------- select (R10-R13-verified logic, two 256-thread halves) ----------
    int w = tid >> 8, t = tid & 255;
    const float* p = (w ? end : start) + (size_t)b * NT;

    int t0 = t * 8;
    float v[8];
    *(float4*)&v[0] = *(const float4*)&p[t0];
    *(float4*)&v[4] = *(const float4*)&p[t0 + 4];

    float m = v[0];
    #pragma unroll
    for (int k = 1; k < 8; k++) m = fmaxf(m, v[k]);
    redS[w * 256 + t] = m;
    __syncthreads();
    for (int s = 128; s > 0; s >>= 1) {
        if (t < s) redS[w * 256 + t] = fmaxf(redS[w * 256 + t], redS[w * 256 + t + s]);
        __syncthreads();
    }
    float thr = 0.5f * redS[w * 256];
    if (t == 0) sMaxA[w] = redS[w * 256];

    float prev = (t == 0)   ? -1.0f : p[t0 - 1];   // t==0: rise pad true
    float next = (t == 255) ? -1.0f : p[t0 + 8];   // t==2047: fall pad true

    bool flag[8];
    int c = 0;
    #pragma unroll
    for (int k = 0; k < 8; k++) {
        float pv = (k == 0) ? prev : v[k - 1];
        float nv = (k == 7) ? next : v[k + 1];
        bool f = ((v[k] > pv) && (v[k] > nv)) || (v[k] > thr);
        flag[k] = f;
        c += f;
    }
    sc2[w][t] = c;
    __syncthreads();
    for (int off = 1; off < 256; off <<= 1) {
        int val = (t >= off) ? sc2[w][t - off] : 0;
        __syncthreads();
        sc2[w][t] += val;
        __syncthreads();
    }
    int pos = sc2[w][t] - c;
    #pragma unroll
    for (int k = 0; k < 8; k++) {
        if (flag[k]) {
            if (w == 0) { lsI[pos] = (short)(t0 + k); lsV[pos] = v[k]; }
            else        { leI[pos] = (short)(t0 + k); evV[pos] = v[k]; }
            pos++;
        }
    }
    if (t == 255) sN[w] = sc2[w][255];
    __syncthreads();

    int mS = sN[0], mE = sN[1];
    float maxE = sMaxA[1];
    float maxP = sMaxA[0] * maxE;

    // ---------- totalValid ----------
    int myTot = 0;
    for (int i = tid; i < mS; i += 512) {
        int sPos = lsI[i];
        int lo2 = 0, hi2 = mE;
        while (lo2 < hi2) { int mid = (lo2 + hi2) >> 1; if (leI[mid] < sPos) lo2 = mid + 1; else hi2 = mid; }
        myTot += mE - lo2;
    }
    int totalValid = reduce512(myTot, tid, red8);

    // ---------- mode 2: fewer than K valid -> all valid pairs win ----------
    if (totalValid < KPROP) {
        if (tid == 0) scnt = 0;
        __syncthreads();
        for (int i = wv; i < mS; i += 8) {
            int sPos = lsI[i];
            for (int jb = 0; jb < mE; jb += 64) {
                int j = jb + lane;
                bool tk = (j < mE) && ((int)leI[j] >= sPos);
                unsigned long long vm = __ballot(tk);
                int cntv = __popcll(vm);
                if (cntv) {
                    int bw = 0;
                    if (lane == 0) bw = atomicAdd(&scnt, cntv);
                    bw = __shfl(bw, 0);
                    if (tk) {
                        int p2 = bw + __popcll(vm & ((1ull << lane) - 1ull));
                        if (p2 < CAP) candFlat[bc + p2] = (unsigned)((sPos << 11) | (int)leI[j]);
                    }
                }
            }
        }
        __syncthreads();
        if (tid == 0) { gMode[b] = 2; gCnt[b] = min(scnt, CAP); }
        return;
    }

    // ---------- min e-value ----------
    float mn = 3.4e38f;
    for (int k = tid; k < mE; k += 512) mn = fminf(mn, evV[k]);
    #pragma unroll
    for (int d = 32; d > 0; d >>= 1) mn = fminf(mn, (float)__shfl_down(mn, d));
    if (lane == 0) redS[wv] = mn;
    __syncthreads();
    float minV = redS[0];
    for (int w2 = 1; w2 < 8; w2++) minV = fminf(minV, redS[w2]);
    __syncthreads();
    float invW = 2047.0f / fmaxf(maxE - minV, 1e-30f);

    // ---------- counting sort of e by value bucket (desc) [verified R12/R13] ----
    for (int k = tid; k < 2048; k += 512) Pmut[k] = 0u;
    __syncthreads();
    for (int k = tid; k < mE; k += 512) {
        float kf = fminf((evV[k] - minV) * invW, 2047.0f);
        int key = (int)kf; if (key < 0) key = 0;
        atomicAdd(&Pmut[2047 - key], 1u);        // asc sk = desc value
    }
    __syncthreads();
    {   // PE[sk] = exclusive prefix; PE[2048..2050] = mE
        int c4[4], sum4 = 0;
        #pragma unroll
        for (int q = 0; q < 4; q++) { c4[q] = (int)Pmut[tid * 4 + q]; sum4 += c4[q]; }
        int tot;
        int base = scan512_excl(sum4, tid, red8, &tot);
        int run = base;
        #pragma unroll
        for (int q = 0; q < 4; q++) { PE[tid * 4 + q] = (short)run; run += c4[q]; }
        if (tid == 0) { PE[2048] = (short)tot; PE[2049] = (short)mE; PE[2050] = (short)mE; }
    }
    __syncthreads();
    for (int k = tid; k < 2048; k += 512) Pmut[k] = (unsigned)(short)PE[k];
    __syncthreads();
    for (int k = tid; k < mE; k += 512) {
        float vE = evV[k];
        float kf = fminf((vE - minV) * invW, 2047.0f);
        int key = (int)kf; if (key < 0) key = 0;
        int p2 = (int)atomicAdd(&Pmut[2047 - key], 1u);
        evVs[p2] = vE; evIs[p2] = leI[k];
    }
    __syncthreads();

    // included(tau, sv) = prefix len: all e in buckets >= bucketOf(tau/sv)-2.
    // Superset of {e: fl(sv*e) >= tau}: float err ~1e-4 bucket << 2-bucket margin.
    auto rowCount = [&](float tau, float sv) -> int {
        float x = tau / sv;
        float kf = fminf((x - minV) * invW, 2050.0f);
        int kk = (int)kf - 2;
        if (kk < -2) kk = -2;
        if (kk > 2048) kk = 2048;
        return (int)PE[2048 - kk];
    };
    auto incOracle = [&](float tau) -> int {
        int my = 0;
        for (int i = tid; i < mS; i += 512) my += rowCount(tau, lsV[i]);
        return reduce512(my, tid, red8);
    };

    // ---------- phase 1: bisect t40 into included in [INC_LO, INC_HI] ----------
    float aP = 0.0f, bP = maxP, t40 = -1.0f;
    for (int it = 0; it < 20; it++) {
        float mid = 0.5f * (aP + bP);
        int inc = incOracle(mid);
        if (inc > INC_HI) aP = mid;
        else { bP = mid; t40 = mid; if (inc >= INC_LO) break; }
    }

    bool ok = false;
    int n = 0;

    if (t40 >= 0.0f) {
        // ---------- compact ACTIVE rows (C > 0) ----------
        __shared__ int sActN;
        {
            int a4[4], na = 0;
            #pragma unroll
            for (int q = 0; q < 4; q++) {
                int i = tid * 4 + q;
                int C = (i < mS) ? rowCount(t40, lsV[i]) : 0;
                a4[q] = C; na += (C > 0);
            }
            int tot;
            int base = scan512_excl(na, tid, red8, &tot);
            int run = base;
            #pragma unroll
            for (int q = 0; q < 4; q++) {
                if (a4[q] > 0) { actI[run] = (short)(tid * 4 + q); actC[run] = (short)a4[q]; run++; }
            }
            if (tid == 0) sActN = tot;
        }
        __syncthreads();
        int actN = sActN;

        // ---------- pass A: store all valid-included + hist + exact cert ----------
        float lo = t40;
        float bscale = 2047.0f / fmaxf(maxP - lo, 1e-30f);
        for (int cc2 = tid; cc2 < 2048; cc2 += 512) Pmut[cc2] = 0u;
        if (tid == 0) scnt = 0;
        __syncthreads();
        int certLoc = 0;
        for (int r = wv; r < actN; r += 8) {               // wave per ACTIVE row
            int i = (int)actI[r];
            float sv = lsV[i]; int sPos = lsI[i];
            int C = (int)actC[r];
            for (int jb = 0; jb < C; jb += 64) {
                int j = jb + lane;
                bool keep = false;
                float prod = 0.0f;
                int eIdx = 0;
                if (j < C) {
                    eIdx = (int)evIs[j];
                    prod = sv * evVs[j];
                    keep = (eIdx >= sPos);
                }
                if (keep) {
                    int key = (int)((prod - lo) * bscale);
                    key = key < 0 ? 0 : (key > 2047 ? 2047 : key);
                    atomicAdd(&Pmut[key], 1u);
                    if (prod >= t40) certLoc++;
                }
                unsigned long long vm = __ballot(keep);
                int cntv = __popcll(vm);
                if (cntv) {
                    int bw = 0;
                    if (lane == 0) bw = atomicAdd(&scnt, cntv);
                    bw = __shfl(bw, 0);
                    if (keep) {
                        int p2 = bw + __popcll(vm & ((1ull << lane) - 1ull));
                        if (p2 < CAP) {
                            candFlat[bc + p2] = (unsigned)((sPos << 11) | eIdx);
                            candBits[bc + p2] = __float_as_uint(prod);
                        }
                    }
                }
            }
        }
        __syncthreads();
        n = scnt;
        __syncthreads();
        int certTot = reduce512(certLoc, tid, red8);
        // cert: >=K stored pairs have prod >= t40  ==>  V32 >= t40  ==>
        // every valid pair with bits >= V32 is included (superset) and stored.
        if (certTot >= KPROP) {
            if (n <= CAP) {
                ok = true;
            } else {
                // ---------- overflow: bucket-cut pass B (R13-verified logic) ----
                dscan(Pmut, 2048, KPROP, tid, cs, &sB, &sNd);
                int bb = sB;
                if (bb >= 1) {
                    int cumBB = (KPROP - sNd) + (int)Pmut[bb];
                    if (cumBB <= CAP) {
                        if (tid == 0) scnt = 0;
                        __syncthreads();
                        for (int r = wv; r < actN; r += 8) {
                            int i = (int)actI[r];
                            float sv = lsV[i]; int sPos = lsI[i];
                            int C = (int)actC[r];
                            for (int jb = 0; jb < C; jb += 64) {
                                int j = jb + lane;
                                bool keep = false;
                                float prod = 0.0f;
                                int eIdx = 0;
                                if (j < C) {
                                    eIdx = (int)evIs[j];
                                    prod = sv * evVs[j];
                                    int key = (int)((prod - lo) * bscale);
                                    key = key < 0 ? 0 : (key > 2047 ? 2047 : key);
                                    keep = (eIdx >= sPos) && (key >= bb);
                                }
                                unsigned long long vm = __ballot(keep);
                                int cntv = __popcll(vm);
                                if (cntv) {
                                    int bw = 0;
                                    if (lane == 0) bw = atomicAdd(&scnt, cntv);
                                    bw = __shfl(bw, 0);
                                    if (keep) {
                                        int p2 = bw + __popcll(vm & ((1ull << lane) - 1ull));
                                        if (p2 < CAP) {
                                            candFlat[bc + p2] = (unsigned)((sPos << 11) | eIdx);
                                            candBits[bc + p2] = __float_as_uint(prod);
                                        }
                                    }
                                }
                            }
                        }
                        __syncthreads();
                        n = scnt;
                        __syncthreads();
                        if (n >= KPROP && n <= CAP) ok = true;
                    }
                }
            }
        }
    }

    if (!ok) {
        // ---------- exact full-scan fallback (R11-verified; pathological only) ----
        auto exactCount = [&](float tau) -> int {
            int my = 0;
            for (int i = wv; i < mS; i += 8) {
                float sv2 = lsV[i]; int sPos = lsI[i];
                for (int jb = 0; jb < mE; jb += 64) {
                    int j = jb + lane;
                    if (j < mE && (int)leI[j] >= sPos && sv2 * evV[j] >= tau) my++;
                }
            }
            return reduce512(my, tid, red8);
        };
        float a3 = 0.0f, b3 = maxP, tau3 = -1.0f;
        for (int it = 0; it < 24; it++) {
            float mid = 0.5f * (a3 + b3);
            int cnt = exactCount(mid);
            if (cnt > CAP) a3 = mid;
            else { b3 = mid; tau3 = mid; if (cnt >= KPROP) break; }
        }
        if (tau3 < 0.0f) tau3 = b3;
        if (tid == 0) scnt = 0;
        __syncthreads();
        for (int i = wv; i < mS; i += 8) {
            float sv2 = lsV[i]; int sPos = lsI[i];
            for (int jb = 0; jb < mE; jb += 64) {
                int j = jb + lane;
                float prod = (j < mE) ? sv2 * evV[j] : 0.0f;
                bool valid = (j < mE) && ((int)leI[j] >= sPos) && (prod >= tau3);
                unsigned long long vm = __ballot(valid);
                int cntv = __popcll(vm);
                if (cntv) {
                    int bw = 0;
                    if (lane == 0) bw = atomicAdd(&scnt, cntv);
                    bw = __shfl(bw, 0);
                    if (valid) {
                        int p2 = bw + __popcll(vm & ((1ull << lane) - 1ull));
                        if (p2 < CAP) {
                            candFlat[bc + p2] = (unsigned)((sPos << 11) | (int)leI[j]);
                            candBits[bc + p2] = __float_as_uint(prod);
                        }
                    }
                }
            }
        }
        __syncthreads();
        n = min(scnt, CAP);
        __syncthreads();
        if (n >= KPROP) ok = true;
    }

    if (!ok) {        // degenerate: emit what we have as mode 2
        if (tid == 0) { gMode[b] = 2; gCnt[b] = n; }
        return;
    }

    // ---------- exact 3-level bit refinement among stored (R10-R13-verified) ----
    for (int cc2 = tid; cc2 < 2048; cc2 += 512) Pmut[cc2] = 0u;
    __syncthreads();
    for (int k = tid; k < n; k += 512) atomicAdd(&Pmut[candBits[bc + k] >> 20], 1u);
    __syncthreads();
    dscan(Pmut, 2048, KPROP, tid, cs, &sB, &sNd);
    unsigned bA = (unsigned)sB;
    int ndA = sNd;
    __syncthreads();

    for (int cc2 = tid; cc2 < 1024; cc2 += 512) Pmut[cc2] = 0u;
    __syncthreads();
    for (int k = tid; k < n; k += 512) {
        unsigned bits = candBits[bc + k];
        if ((bits >> 20) == bA) atomicAdd(&Pmut[(bits >> 10) & 1023], 1u);
    }
    __syncthreads();
    dscan(Pmut, 1024, ndA, tid, cs, &sB, &sNd);
    unsigned pref20 = (bA << 10) | (unsigned)sB;
    int ndB = sNd;
    __syncthreads();

    for (int cc2 = tid; cc2 < 1024; cc2 += 512) Pmut[cc2] = 0u;
    __syncthreads();
    for (int k = tid; k < n; k += 512) {
        unsigned bits = candBits[bc + k];
        if ((bits >> 10) == pref20) atomicAdd(&Pmut[bits & 1023], 1u);
    }
    __syncthreads();
    dscan(Pmut, 1024, ndB, tid, cs, &sB, &sNd);

    if (tid == 0) {
        gV32[b] = (pref20 << 10) | (unsigned)sB;   // exact K-th score bits
        gNd2[b] = sNd;                             // ties to keep at V32
        gMode[b] = 1;
        gCnt[b]  = n;
    }
}

// K2: scatter 1.0s after K1's fill.  [verified R9-R13]
__global__ __launch_bounds__(512) void k_emit(
        const int* __restrict__ gMode, const unsigned* __restrict__ gV32,
        const int* __restrict__ gNd2, const int* __restrict__ gCnt,
        const unsigned* __restrict__ candFlat, const unsigned* __restrict__ candBits,
        float* __restrict__ out) {
    int b = blockIdx.x, tid = threadIdx.x;
    int md = gMode[b], n = gCnt[b];
    const unsigned* cf = candFlat + (size_t)b * CAP;

    if (md == 2) {
        for (int k = tid; k < n; k += 512) {
            unsigned f = cf[k];
            int s = (int)(f >> 11), e = (int)(f & 2047u);
            out[((size_t)b * NT + (e - s)) * NT + s] = 1.0f;
        }
        return;
    }

    __shared__ unsigned tie[TIE_CAP];
    __shared__ int tieCnt;
    if (tid == 0) tieCnt = 0;
    __syncthreads();

    unsigned V32 = gV32[b];
    int nd2 = gNd2[b];
    const unsigned* cb = candBits + (size_t)b * CAP;

    for (int k = tid; k < n; k += 512) {
        unsigned bits = cb[k];
        unsigned f = cf[k];
        if (bits > V32) {
            int s = (int)(f >> 11), e = (int)(f & 2047u);
            out[((size_t)b * NT + (e - s)) * NT + s] = 1.0f;
        } else if (bits == V32) {
            int pp = atomicAdd(&tieCnt, 1);
            if (pp < TIE_CAP) tie[pp] = f;
        }
    }
    __syncthreads();
    int tn = min(tieCnt, TIE_CAP);
    for (int k = tid; k < tn; k += 512) {
        unsigned f = tie[k];
        int rank = 0;
        for (int j = 0; j < tn; j++) rank += (tie[j] < f) ? 1 : 0;
        if (rank < nd2) {                 // lowest flat indices win (lax.top_k)
            int s = (int)(f >> 11), e = (int)(f & 2047u);
            out[((size_t)b * NT + (e - s)) * NT + s] = 1.0f;
        }
    }
}

extern "C" void kernel_launch(void* const* d_in, const int* in_sizes, int n_in,
                              void* d_out, int out_size, void* d_ws, size_t ws_size,
                              hipStream_t stream) {
    const float* start = (const float*)d_in[0];
    const float* end   = (const float*)d_in[1];
    // d_in[2] (actionness) unused by the reference.
    float* out = (float*)d_out;
    char* ws = (char*)d_ws;

    int*      gMode    = (int*)     (ws + 0);
    unsigned* gV32     = (unsigned*)(ws + 64);
    int*      gNd2     = (int*)     (ws + 128);
    int*      gCnt     = (int*)     (ws + 192);
    unsigned* candFlat = (unsigned*)(ws + 4096);
    unsigned* candBits = (unsigned*)(ws + 528384);

    // K1: 16 per-batch work blocks (~35 us) + 2048 fill blocks (268 MB zero)
    k_main<<<NB + 2048, 512, 0, stream>>>(start, end, (float4*)out,
                                          gMode, gV32, gNd2, gCnt,
                                          candFlat, candBits);
    // K2: scatter winners/ties, strictly after the fill completes.
    k_emit<<<NB, 512, 0, stream>>>(gMode, gV32, gNd2, gCnt, candFlat, candBits, out);
}

// Round 16
// 74.141 us; speedup vs baseline: 1.0605x; 1.0605x over previous
//
#include <hip/hip_runtime.h>

// Problem constants (B=16, T=2048 fixed by setup_inputs)
constexpr int NB = 16;
constexpr int NT = 2048;
constexpr int KPROP = 2000;
constexpr int CAP = 8192;       // candidate cap
constexpr int TIE_CAP = 2048;

// ---------------------------------------------------------------------------
// ws layout (bytes):
//   0      : gMode[16] int   (1 = threshold scatter, 2 = all-candidates)
//   64     : gV32[16]  u32   (exact 32-bit K-th score bit pattern)
//   128    : gNd2[16]  int   (ties at V32 still to keep)
//   192    : gCnt[16]  int   (candidate count)
//   4096   : candFlat[16][8192] u32  (flat = s*2048+e)      512 KB
//   528384 : candBits[16][8192] u32  (score bit pattern)    512 KB
// ---------------------------------------------------------------------------

// Descending scan over nbuck-bucket histogram.  [verified R9-R15]
__device__ void dscan(const unsigned* __restrict__ h, int nbuck, int nd, int tid,
                      int* cs, int* oB, int* oNd) {
    int chunk = nbuck >> 8;
    if (tid < 256) {
        int base = tid * chunk, s2 = 0;
        for (int c = 0; c < chunk; c++) s2 += (int)h[base + c];
        cs[tid] = s2;
    }
    __syncthreads();
    if (tid == 0) {
        int acc = 0, tc = -1;
        for (int t2 = 255; t2 >= 0; t2--) {
            if (acc + cs[t2] >= nd) { tc = t2; break; }
            acc += cs[t2];
        }
        int found = -1;
        if (tc >= 0) {
            for (int c = tc * chunk + chunk - 1; c >= tc * chunk; c--) {
                int cnt = (int)h[c];
                if (acc + cnt >= nd) { found = c; break; }
                acc += cnt;
            }
        }
        *oB = found;
        *oNd = nd - acc;
    }
    __syncthreads();
}

// Exclusive block scan over 512 per-thread ints.  [verified R11-R15]
__device__ int scan512_excl(int x, int tid, volatile int* wsum, int* totOut) {
    int lane = tid & 63, wv = tid >> 6;
    int inc = x;
    #pragma unroll
    for (int d = 1; d < 64; d <<= 1) {
        int y = __shfl_up(inc, d);
        if (lane >= d) inc += y;
    }
    if (lane == 63) wsum[wv] = inc;
    __syncthreads();
    int base = 0, tot = 0;
    for (int w2 = 0; w2 < 8; w2++) {
        int v2 = wsum[w2];
        if (w2 < wv) base += v2;
        tot += v2;
    }
    __syncthreads();
    *totOut = tot;
    return base + (inc - x);
}

// Block-wide int sum; all threads receive the total.  [verified R11-R15]
__device__ int reduce512(int x, int tid, volatile int* wsum) {
    int lane = tid & 63, wv = tid >> 6;
    #pragma unroll
    for (int d = 32; d > 0; d >>= 1) x += __shfl_down(x, d);
    if (lane == 0) wsum[wv] = x;
    __syncthreads();
    int tot = 0;
    for (int w2 = 0; w2 < 8; w2++) tot += wsum[w2];
    __syncthreads();
    return tot;
}

// K1: blocks [16, 2064) zero the 268 MB output. Blocks [0,16): one batch each:
// select (shfl scan/max) -> counting-sort e by value (row's included set =
// PREFIX of evVs) -> phase-1 FALSE-POSITION on bucket-prefix oracle -> compact
// ACTIVE rows -> pass A: store valid-included pairs + value-linear histogram
// + exact cert #(prod>=t40) -> (rare) overflow bucket-cut pass B -> 3-level
// bit refinement -> persist. Exact full-scan fallback if cert fails.
__global__ __launch_bounds__(512) void k_main(
        const float* __restrict__ start, const float* __restrict__ end,
        float4* __restrict__ out4,
        int* __restrict__ gMode, unsigned* __restrict__ gV32,
        int* __restrict__ gNd2, int* __restrict__ gCnt,
        unsigned* __restrict__ candFlat, unsigned* __restrict__ candBits) {
    int blk = blockIdx.x, tid = threadIdx.x;
    if (blk >= NB) {                     // ---- fill path: 131072 B per block ----
        float4 z = make_float4(0.f, 0.f, 0.f, 0.f);
        size_t base = (size_t)(blk - NB) * 8192 + tid;
        #pragma unroll
        for (int it = 0; it < 16; it++) out4[base + (size_t)it * 512] = z;
        return;
    }
    int b = blk;
    size_t bc = (size_t)b * CAP;

    __shared__ short lsI[NT];  __shared__ float lsV[NT];    // s anchors, idx order
    __shared__ short leI[NT];  __shared__ float evV[NT];    // e anchors, idx order
    __shared__ float evVs[NT]; __shared__ short evIs[NT];   // e, bucket-desc sorted
    __shared__ short actI[NT]; __shared__ short actC[NT];   // active rows + counts
    __shared__ unsigned Pmut[2048];      // bucket hist -> scatter ctr -> prod hist
    __shared__ short PE[2051];           // exclusive prefix over desc-bucket key
    __shared__ float redS[8];
    __shared__ int   red8[8];
    __shared__ int   cs[256];
    __shared__ float sMaxA[2];
    __shared__ int   sN[2];
    __shared__ int   scnt, sB, sNd;

    int lane = tid & 63, wv = tid >> 6;

    // ---------- select (R15 logic; shfl scan + shfl max, 4 barriers) ----------
    int w = tid >> 8, t = tid & 255;
    const float* p = (w ? end : start) + (size_t)b * NT;

    int t0 = t * 8;
    float v[8];
    *(float4*)&v[0] = *(const float4*)&p[t0];
    *(float4*)&v[4] = *(const float4*)&p[t0 + 4];

    float m = v[0];
    #pragma unroll
    for (int k = 1; k < 8; k++) m = fmaxf(m, v[k]);
    #pragma unroll
    for (int d = 32; d > 0; d >>= 1) m = fmaxf(m, (float)__shfl_down(m, d));
    if (lane == 0) redS[wv] = m;
    __syncthreads();
    float rowMax = fmaxf(fmaxf(redS[w * 4 + 0], redS[w * 4 + 1]),
                         fmaxf(redS[w * 4 + 2], redS[w * 4 + 3]));
    float thr = 0.5f * rowMax;
    if (t == 0) sMaxA[w] = rowMax;

    float prev = (t == 0)   ? -1.0f : p[t0 - 1];   // t==0: rise pad true
    float next = (t == 255) ? -1.0f : p[t0 + 8];   // t==2047: fall pad true

    bool flag[8];
    int c = 0;
    #pragma unroll
    for (int k = 0; k < 8; k++) {
        float pv = (k == 0) ? prev : v[k - 1];
        float nv = (k == 7) ? next : v[k + 1];
        bool f = ((v[k] > pv) && (v[k] > nv)) || (v[k] > thr);
        flag[k] = f;
        c += f;
    }
    // exclusive scan within each 256-thread half (wave shfl + 4 wave sums)
    int inc = c;
    #pragma unroll
    for (int d = 1; d < 64; d <<= 1) {
        int y = __shfl_up(inc, d);
        if (lane >= d) inc += y;
    }
    if (lane == 63) red8[wv] = inc;
    __syncthreads();
    int base0 = 0;
    #pragma unroll
    for (int q = 0; q < 4; q++) {
        int vq = red8[w * 4 + q];
        if (q < (t >> 6)) base0 += vq;
    }
    int halfTot = red8[w * 4] + red8[w * 4 + 1] + red8[w * 4 + 2] + red8[w * 4 + 3];
    int pos = base0 + (inc - c);
    #pragma unroll
    for (int k = 0; k < 8; k++) {
        if (flag[k]) {
            if (w == 0) { lsI[pos] = (short)(t0 + k); lsV[pos] = v[k]; }
            else        { leI[pos] = (short)(t0 + k); evV[pos] = v[k]; }
            pos++;
        }
    }
    if (t == 0) sN[w] = halfTot;
    __syncthreads();

    int mS = sN[0], mE = sN[1];
    float maxE = sMaxA[1];
    float maxP = sMaxA[0] * maxE;

    // ---------- totalValid ----------
    int myTot = 0;
    for (int i = tid; i < mS; i += 512) {
        int sPos = lsI[i];
        int lo2 = 0, hi2 = mE;
        while (lo2 < hi2) { int mid = (lo2 + hi2) >> 1; if (leI[mid] < sPos) lo2 = mid + 1; else hi2 = mid; }
        myTot += mE - lo2;
    }
    int totalValid = reduce512(myTot, tid, red8);

    // ---------- mode 2: fewer than K valid -> all valid pairs win ----------
    if (totalValid < KPROP) {
        if (tid == 0) scnt = 0;
        __syncthreads();
        for (int i = wv; i < mS; i += 8) {
            int sPos = lsI[i];
            for (int jb = 0; jb < mE; jb += 64) {
                int j = jb + lane;
                bool tk = (j < mE) && ((int)leI[j] >= sPos);
                unsigned long long vm = __ballot(tk);
                int cntv = __popcll(vm);
                if (cntv) {
                    int bw = 0;
                    if (lane == 0) bw = atomicAdd(&scnt, cntv);
                    bw = __shfl(bw, 0);
                    if (tk) {
                        int p2 = bw + __popcll(vm & ((1ull << lane) - 1ull));
                        if (p2 < CAP) candFlat[bc + p2] = (unsigned)((sPos << 11) | (int)leI[j]);
                    }
                }
            }
        }
        __syncthreads();
        if (tid == 0) { gMode[b] = 2; gCnt[b] = min(scnt, CAP); }
        return;
    }

    // ---------- min e-value ----------
    float mn = 3.4e38f;
    for (int k = tid; k < mE; k += 512) mn = fminf(mn, evV[k]);
    #pragma unroll
    for (int d = 32; d > 0; d >>= 1) mn = fminf(mn, (float)__shfl_down(mn, d));
    if (lane == 0) redS[wv] = mn;
    __syncthreads();
    float minV = redS[0];
    for (int w2 = 1; w2 < 8; w2++) minV = fminf(minV, redS[w2]);
    __syncthreads();
    float invW = 2047.0f / fmaxf(maxE - minV, 1e-30f);

    // ---------- counting sort of e by value bucket (desc) [verified R12-R15] ----
    for (int k = tid; k < 2048; k += 512) Pmut[k] = 0u;
    __syncthreads();
    for (int k = tid; k < mE; k += 512) {
        float kf = fminf((evV[k] - minV) * invW, 2047.0f);
        int key = (int)kf; if (key < 0) key = 0;
        atomicAdd(&Pmut[2047 - key], 1u);        // asc sk = desc value
    }
    __syncthreads();
    {   // PE[sk] = exclusive prefix; PE[2048..2050] = mE
        int c4[4], sum4 = 0;
        #pragma unroll
        for (int q = 0; q < 4; q++) { c4[q] = (int)Pmut[tid * 4 + q]; sum4 += c4[q]; }
        int tot;
        int base = scan512_excl(sum4, tid, red8, &tot);
        int run = base;
        #pragma unroll
        for (int q = 0; q < 4; q++) { PE[tid * 4 + q] = (short)run; run += c4[q]; }
        if (tid == 0) { PE[2048] = (short)tot; PE[2049] = (short)mE; PE[2050] = (short)mE; }
    }
    __syncthreads();
    for (int k = tid; k < 2048; k += 512) Pmut[k] = (unsigned)(short)PE[k];
    __syncthreads();
    for (int k = tid; k < mE; k += 512) {
        float vE = evV[k];
        float kf = fminf((vE - minV) * invW, 2047.0f);
        int key = (int)kf; if (key < 0) key = 0;
        int p2 = (int)atomicAdd(&Pmut[2047 - key], 1u);
        evVs[p2] = vE; evIs[p2] = leI[k];
    }
    __syncthreads();

    // included(tau, sv) = prefix len: all e in buckets >= bucketOf(tau/sv)-2.
    // Superset of {e: fl(sv*e) >= tau}: float err ~1e-4 bucket << 2-bucket margin.
    auto rowCount = [&](float tau, float sv) -> int {
        float x = tau / sv;
        float kf = fminf((x - minV) * invW, 2050.0f);
        int kk = (int)kf - 2;
        if (kk < -2) kk = -2;
        if (kk > 2048) kk = 2048;
        return (int)PE[2048 - kk];
    };
    auto incOracle = [&](float tau) -> int {
        int my = 0;
        for (int i = tid; i < mS; i += 512) my += rowCount(tau, lsV[i]);
        return reduce512(my, tid, red8);
    };

    // ---------- phase 1: FALSE-POSITION on included count, window [5000,13000] ----
    float aT = 0.0f, bT = maxP;
    float Fa = (float)mS * (float)mE;    // = incOracle(0)
    float Fb = 0.0f;
    float t40 = -1.0f;
    for (int it = 0; it < 12; it++) {
        float mid;
        float denom = Fa - Fb;
        if (denom > 1.0f) {
            mid = aT + (bT - aT) * ((Fa - 9000.0f) / denom);
            if (!(mid > aT && mid < bT)) mid = 0.5f * (aT + bT);
        } else mid = 0.5f * (aT + bT);
        int incC = incOracle(mid);
        if (incC > 13000) { aT = mid; Fa = (float)incC; }
        else if (incC < 5000) { bT = mid; Fb = (float)incC; }
        else { t40 = mid; break; }
    }
    // salvage: aT's included count is known <= 24576 -> enumeration still cheap;
    // certification + overflow-cut keep it exact. (aT may be 0: include all.)
    if (t40 < 0.0f && Fa <= 24576.0f) t40 = aT;

    bool ok = false;
    int n = 0;

    if (t40 >= 0.0f) {
        // ---------- compact ACTIVE rows (C > 0) [verified R15] ----------
        __shared__ int sActN;
        {
            int a4[4], na = 0;
            #pragma unroll
            for (int q = 0; q < 4; q++) {
                int i = tid * 4 + q;
                int C = (i < mS) ? rowCount(t40, lsV[i]) : 0;
                a4[q] = C; na += (C > 0);
            }
            int tot;
            int base = scan512_excl(na, tid, red8, &tot);
            int run = base;
            #pragma unroll
            for (int q = 0; q < 4; q++) {
                if (a4[q] > 0) { actI[run] = (short)(tid * 4 + q); actC[run] = (short)a4[q]; run++; }
            }
            if (tid == 0) sActN = tot;
        }
        __syncthreads();
        int actN = sActN;

        // ---------- pass A: store all valid-included + hist + exact cert ----------
        float lo = t40;
        float bscale = 2047.0f / fmaxf(maxP - lo, 1e-30f);
        for (int cc2 = tid; cc2 < 2048; cc2 += 512) Pmut[cc2] = 0u;
        if (tid == 0) scnt = 0;
        __syncthreads();
        int certLoc = 0;
        for (int r = wv; r < actN; r += 8) {               // wave per ACTIVE row
            int i = (int)actI[r];
            float sv = lsV[i]; int sPos = lsI[i];
            int C = (int)actC[r];
            for (int jb = 0; jb < C; jb += 64) {
                int j = jb + lane;
                bool keep = false;
                float prod = 0.0f;
                int eIdx = 0;
                if (j < C) {
                    eIdx = (int)evIs[j];
                    prod = sv * evVs[j];
                    keep = (eIdx >= sPos);
                }
                if (keep) {
                    int key = (int)((prod - lo) * bscale);
                    key = key < 0 ? 0 : (key > 2047 ? 2047 : key);
                    atomicAdd(&Pmut[key], 1u);
                    if (prod >= t40) certLoc++;
                }
                unsigned long long vm = __ballot(keep);
                int cntv = __popcll(vm);
                if (cntv) {
                    int bw = 0;
                    if (lane == 0) bw = atomicAdd(&scnt, cntv);
                    bw = __shfl(bw, 0);
                    if (keep) {
                        int p2 = bw + __popcll(vm & ((1ull << lane) - 1ull));
                        if (p2 < CAP) {
                            candFlat[bc + p2] = (unsigned)((sPos << 11) | eIdx);
                            candBits[bc + p2] = __float_as_uint(prod);
                        }
                    }
                }
            }
        }
        __syncthreads();
        n = scnt;
        __syncthreads();
        int certTot = reduce512(certLoc, tid, red8);
        // cert: >=K stored pairs have prod >= t40  ==>  V32 >= t40  ==>
        // every valid pair with bits >= V32 is included (superset) and stored.
        if (certTot >= KPROP) {
            if (n <= CAP) {
                ok = true;
            } else {
                // ---------- overflow: bucket-cut pass B (R13/R15-verified) ----
                dscan(Pmut, 2048, KPROP, tid, cs, &sB, &sNd);
                int bb = sB;
                if (bb >= 1) {
                    int cumBB = (KPROP - sNd) + (int)Pmut[bb];
                    if (cumBB <= CAP) {
                        if (tid == 0) scnt = 0;
                        __syncthreads();
                        for (int r = wv; r < actN; r += 8) {
                            int i = (int)actI[r];
                            float sv = lsV[i]; int sPos = lsI[i];
                            int C = (int)actC[r];
                            for (int jb = 0; jb < C; jb += 64) {
                                int j = jb + lane;
                                bool keep = false;
                                float prod = 0.0f;
                                int eIdx = 0;
                                if (j < C) {
                                    eIdx = (int)evIs[j];
                                    prod = sv * evVs[j];
                                    int key = (int)((prod - lo) * bscale);
                                    key = key < 0 ? 0 : (key > 2047 ? 2047 : key);
                                    keep = (eIdx >= sPos) && (key >= bb);
                                }
                                unsigned long long vm = __ballot(keep);
                                int cntv = __popcll(vm);
                                if (cntv) {
                                    int bw = 0;
                                    if (lane == 0) bw = atomicAdd(&scnt, cntv);
                                    bw = __shfl(bw, 0);
                                    if (keep) {
                                        int p2 = bw + __popcll(vm & ((1ull << lane) - 1ull));
                                        if (p2 < CAP) {
                                            candFlat[bc + p2] = (unsigned)((sPos << 11) | eIdx);
                                            candBits[bc + p2] = __float_as_uint(prod);
                                        }
                                    }
                                }
                            }
                        }
                        __syncthreads();
                        n = scnt;
                        __syncthreads();
                        if (n >= KPROP && n <= CAP) ok = true;
                    }
                }
            }
        }
    }

    if (!ok) {
        // ---------- exact full-scan fallback (R11-verified; pathological only) ----
        auto exactCount = [&](float tau) -> int {
            int my = 0;
            for (int i = wv; i < mS; i += 8) {
                float sv2 = lsV[i]; int sPos = lsI[i];
                for (int jb = 0; jb < mE; jb += 64) {
                    int j = jb + lane;
                    if (j < mE && (int)leI[j] >= sPos && sv2 * evV[j] >= tau) my++;
                }
            }
            return reduce512(my, tid, red8);
        };
        float a3 = 0.0f, b3 = maxP, tau3 = -1.0f;
        for (int it = 0; it < 24; it++) {
            float mid = 0.5f * (a3 + b3);
            int cnt = exactCount(mid);
            if (cnt > CAP) a3 = mid;
            else { b3 = mid; tau3 = mid; if (cnt >= KPROP) break; }
        }
        if (tau3 < 0.0f) tau3 = b3;
        if (tid == 0) scnt = 0;
        __syncthreads();
        for (int i = wv; i < mS; i += 8) {
            float sv2 = lsV[i]; int sPos = lsI[i];
            for (int jb = 0; jb < mE; jb += 64) {
                int j = jb + lane;
                float prod = (j < mE) ? sv2 * evV[j] : 0.0f;
                bool valid = (j < mE) && ((int)leI[j] >= sPos) && (prod >= tau3);
                unsigned long long vm = __ballot(valid);
                int cntv = __popcll(vm);
                if (cntv) {
                    int bw = 0;
                    if (lane == 0) bw = atomicAdd(&scnt, cntv);
                    bw = __shfl(bw, 0);
                    if (valid) {
                        int p2 = bw + __popcll(vm & ((1ull << lane) - 1ull));
                        if (p2 < CAP) {
                            candFlat[bc + p2] = (unsigned)((sPos << 11) | (int)leI[j]);
                            candBits[bc + p2] = __float_as_uint(prod);
                        }
                    }
                }
            }
        }
        __syncthreads();
        n = min(scnt, CAP);
        __syncthreads();
        if (n >= KPROP) ok = true;
    }

    if (!ok) {        // degenerate: emit what we have as mode 2
        if (tid == 0) { gMode[b] = 2; gCnt[b] = n; }
        return;
    }

    // ---------- exact 3-level bit refinement among stored (R10-R15-verified) ----
    for (int cc2 = tid; cc2 < 2048; cc2 += 512) Pmut[cc2] = 0u;
    __syncthreads();
    for (int k = tid; k < n; k += 512) atomicAdd(&Pmut[candBits[bc + k] >> 20], 1u);
    __syncthreads();
    dscan(Pmut, 2048, KPROP, tid, cs, &sB, &sNd);
    unsigned bA = (unsigned)sB;
    int ndA = sNd;
    __syncthreads();

    for (int cc2 = tid; cc2 < 1024; cc2 += 512) Pmut[cc2] = 0u;
    __syncthreads();
    for (int k = tid; k < n; k += 512) {
        unsigned bits = candBits[bc + k];
        if ((bits >> 20) == bA) atomicAdd(&Pmut[(bits >> 10) & 1023], 1u);
    }
    __syncthreads();
    dscan(Pmut, 1024, ndA, tid, cs, &sB, &sNd);
    unsigned pref20 = (bA << 10) | (unsigned)sB;
    int ndB = sNd;
    __syncthreads();

    for (int cc2 = tid; cc2 < 1024; cc2 += 512) Pmut[cc2] = 0u;
    __syncthreads();
    for (int k = tid; k < n; k += 512) {
        unsigned bits = candBits[bc + k];
        if ((bits >> 10) == pref20) atomicAdd(&Pmut[bits & 1023], 1u);
    }
    __syncthreads();
    dscan(Pmut, 1024, ndB, tid, cs, &sB, &sNd);

    if (tid == 0) {
        gV32[b] = (pref20 << 10) | (unsigned)sB;   // exact K-th score bits
        gNd2[b] = sNd;                             // ties to keep at V32
        gMode[b] = 1;
        gCnt[b]  = n;
    }
}

// K2: scatter 1.0s after K1's fill.  [verified R9-R15]
__global__ __launch_bounds__(512) void k_emit(
        const int* __restrict__ gMode, const unsigned* __restrict__ gV32,
        const int* __restrict__ gNd2, const int* __restrict__ gCnt,
        const unsigned* __restrict__ candFlat, const unsigned* __restrict__ candBits,
        float* __restrict__ out) {
    int b = blockIdx.x, tid = threadIdx.x;
    int md = gMode[b], n = gCnt[b];
    const unsigned* cf = candFlat + (size_t)b * CAP;

    if (md == 2) {
        for (int k = tid; k < n; k += 512) {
            unsigned f = cf[k];
            int s = (int)(f >> 11), e = (int)(f & 2047u);
            out[((size_t)b * NT + (e - s)) * NT + s] = 1.0f;
        }
        return;
    }

    __shared__ unsigned tie[TIE_CAP];
    __shared__ int tieCnt;
    if (tid == 0) tieCnt = 0;
    __syncthreads();

    unsigned V32 = gV32[b];
    int nd2 = gNd2[b];
    const unsigned* cb = candBits + (size_t)b * CAP;

    for (int k = tid; k < n; k += 512) {
        unsigned bits = cb[k];
        unsigned f = cf[k];
        if (bits > V32) {
            int s = (int)(f >> 11), e = (int)(f & 2047u);
            out[((size_t)b * NT + (e - s)) * NT + s] = 1.0f;
        } else if (bits == V32) {
            int pp = atomicAdd(&tieCnt, 1);
            if (pp < TIE_CAP) tie[pp] = f;
        }
    }
    __syncthreads();
    int tn = min(tieCnt, TIE_CAP);
    for (int k = tid; k < tn; k += 512) {
        unsigned f = tie[k];
        int rank = 0;
        for (int j = 0; j < tn; j++) rank += (tie[j] < f) ? 1 : 0;
        if (rank < nd2) {                 // lowest flat indices win (lax.top_k)
            int s = (int)(f >> 11), e = (int)(f & 2047u);
            out[((size_t)b * NT + (e - s)) * NT + s] = 1.0f;
        }
    }
}

extern "C" void kernel_launch(void* const* d_in, const int* in_sizes, int n_in,
                              void* d_out, int out_size, void* d_ws, size_t ws_size,
                              hipStream_t stream) {
    const float* start = (const float*)d_in[0];
    const float* end   = (const float*)d_in[1];
    // d_in[2] (actionness) unused by the reference.
    float* out = (float*)d_out;
    char* ws = (char*)d_ws;

    int*      gMode    = (int*)     (ws + 0);
    unsigned* gV32     = (unsigned*)(ws + 64);
    int*      gNd2     = (int*)     (ws + 128);
    int*      gCnt     = (int*)     (ws + 192);
    unsigned* candFlat = (unsigned*)(ws + 4096);
    unsigned* candBits = (unsigned*)(ws + 528384);

    // K1: 16 per-batch work blocks (~45 us target) + 2048 fill blocks (268 MB)
    k_main<<<NB + 2048, 512, 0, stream>>>(start, end, (float4*)out,
                                          gMode, gV32, gNd2, gCnt,
                                          candFlat, candBits);
    // K2: scatter winners/ties, strictly after the fill completes.
    k_emit<<<NB, 512, 0, stream>>>(gMode, gV32, gNd2, gCnt, candFlat, candBits, out);
}

// Round 17
// 59.820 us; speedup vs baseline: 1.3144x; 1.2394x over previous
//
#include <hip/hip_runtime.h>

// Problem constants (B=16, T=2048 fixed by setup_inputs)
constexpr int NB = 16;
constexpr int NT = 2048;
constexpr int KPROP = 2000;
constexpr int CAP = 8192;       // candidate cap
constexpr int TIE_CAP = 2048;
constexpr int TB_CAP = 1024;    // tiny-bucket refinement capacity

// ---------------------------------------------------------------------------
// ws layout (bytes):
//   0      : gMode[16] int   (1 = threshold scatter, 2 = all-candidates)
//   64     : gV32[16]  u32   (exact 32-bit K-th score bit pattern)
//   128    : gNd2[16]  int   (ties at V32 still to keep)
//   192    : gCnt[16]  int   (candidate count)
//   4096   : candFlat[16][8192] u32  (flat = s*2048+e)      512 KB
//   528384 : candBits[16][8192] u32  (score bit pattern)    512 KB
// ---------------------------------------------------------------------------

// Descending scan over nbuck-bucket histogram.  [verified R9-R16]
__device__ void dscan(const unsigned* __restrict__ h, int nbuck, int nd, int tid,
                      int* cs, int* oB, int* oNd) {
    int chunk = nbuck >> 8;
    if (tid < 256) {
        int base = tid * chunk, s2 = 0;
        for (int c = 0; c < chunk; c++) s2 += (int)h[base + c];
        cs[tid] = s2;
    }
    __syncthreads();
    if (tid == 0) {
        int acc = 0, tc = -1;
        for (int t2 = 255; t2 >= 0; t2--) {
            if (acc + cs[t2] >= nd) { tc = t2; break; }
            acc += cs[t2];
        }
        int found = -1;
        if (tc >= 0) {
            for (int c = tc * chunk + chunk - 1; c >= tc * chunk; c--) {
                int cnt = (int)h[c];
                if (acc + cnt >= nd) { found = c; break; }
                acc += cnt;
            }
        }
        *oB = found;
        *oNd = nd - acc;
    }
    __syncthreads();
}

// Exclusive block scan over 512 per-thread ints.  [verified R11-R16]
__device__ int scan512_excl(int x, int tid, volatile int* wsum, int* totOut) {
    int lane = tid & 63, wv = tid >> 6;
    int inc = x;
    #pragma unroll
    for (int d = 1; d < 64; d <<= 1) {
        int y = __shfl_up(inc, d);
        if (lane >= d) inc += y;
    }
    if (lane == 63) wsum[wv] = inc;
    __syncthreads();
    int base = 0, tot = 0;
    for (int w2 = 0; w2 < 8; w2++) {
        int v2 = wsum[w2];
        if (w2 < wv) base += v2;
        tot += v2;
    }
    __syncthreads();
    *totOut = tot;
    return base + (inc - x);
}

// Block-wide int sum; all threads receive the total.  [verified R11-R16]
__device__ int reduce512(int x, int tid, volatile int* wsum) {
    int lane = tid & 63, wv = tid >> 6;
    #pragma unroll
    for (int d = 32; d > 0; d >>= 1) x += __shfl_down(x, d);
    if (lane == 0) wsum[wv] = x;
    __syncthreads();
    int tot = 0;
    for (int w2 = 0; w2 < 8; w2++) tot += wsum[w2];
    __syncthreads();
    return tot;
}

// K1: blocks [16, 2064) zero the 268 MB output. Blocks [0,16): one batch each:
// select -> counting-sort e by value (row's included set = PREFIX of evVs) ->
// phase-1 false-position IN WAVE 0 (no block barriers per eval) -> compact
// ACTIVE rows -> pass A: store valid-included pairs + value-linear histogram
// + exact cert -> (rare) overflow bucket-cut pass B -> TINY-BUCKET exact
// refinement (3-level kept as guard path) -> persist. Full-scan fallback.
__global__ __launch_bounds__(512) void k_main(
        const float* __restrict__ start, const float* __restrict__ end,
        float4* __restrict__ out4,
        int* __restrict__ gMode, unsigned* __restrict__ gV32,
        int* __restrict__ gNd2, int* __restrict__ gCnt,
        unsigned* __restrict__ candFlat, unsigned* __restrict__ candBits) {
    int blk = blockIdx.x, tid = threadIdx.x;
    if (blk >= NB) {                     // ---- fill path: 131072 B per block ----
        float4 z = make_float4(0.f, 0.f, 0.f, 0.f);
        size_t base = (size_t)(blk - NB) * 8192 + tid;
        #pragma unroll
        for (int it = 0; it < 16; it++) out4[base + (size_t)it * 512] = z;
        return;
    }
    int b = blk;
    size_t bc = (size_t)b * CAP;

    __shared__ short lsI[NT];  __shared__ float lsV[NT];    // s anchors, idx order
    __shared__ short leI[NT];  __shared__ float evV[NT];    // e anchors, idx order
    __shared__ float evVs[NT]; __shared__ short evIs[NT];   // e, bucket-desc sorted
    __shared__ short actI[NT]; __shared__ short actC[NT];   // active rows + counts
    __shared__ unsigned Pmut[2048];      // bucket hist -> scatter ctr -> prod hist
    __shared__ short PE[2051];           // exclusive prefix over desc-bucket key
    __shared__ unsigned tb[TB_CAP];      // tiny-bucket refinement buffer
    __shared__ float redS[8];
    __shared__ int   red8[8];
    __shared__ int   cs[256];
    __shared__ float sMaxA[2];
    __shared__ int   sN[2];
    __shared__ int   scnt, sB, sNd, tbCnt, sFlag;
    __shared__ float sT40;

    int lane = tid & 63, wv = tid >> 6;

    // ---------- select (R16-verified; shfl scan + shfl max) ----------
    int w = tid >> 8, t = tid & 255;
    const float* p = (w ? end : start) + (size_t)b * NT;

    int t0 = t * 8;
    float v[8];
    *(float4*)&v[0] = *(const float4*)&p[t0];
    *(float4*)&v[4] = *(const float4*)&p[t0 + 4];

    float m = v[0];
    #pragma unroll
    for (int k = 1; k < 8; k++) m = fmaxf(m, v[k]);
    #pragma unroll
    for (int d = 32; d > 0; d >>= 1) m = fmaxf(m, (float)__shfl_down(m, d));
    if (lane == 0) redS[wv] = m;
    __syncthreads();
    float rowMax = fmaxf(fmaxf(redS[w * 4 + 0], redS[w * 4 + 1]),
                         fmaxf(redS[w * 4 + 2], redS[w * 4 + 3]));
    float thr = 0.5f * rowMax;
    if (t == 0) sMaxA[w] = rowMax;

    float prev = (t == 0)   ? -1.0f : p[t0 - 1];   // t==0: rise pad true
    float next = (t == 255) ? -1.0f : p[t0 + 8];   // t==2047: fall pad true

    bool flag[8];
    int c = 0;
    #pragma unroll
    for (int k = 0; k < 8; k++) {
        float pv = (k == 0) ? prev : v[k - 1];
        float nv = (k == 7) ? next : v[k + 1];
        bool f = ((v[k] > pv) && (v[k] > nv)) || (v[k] > thr);
        flag[k] = f;
        c += f;
    }
    int inc = c;
    #pragma unroll
    for (int d = 1; d < 64; d <<= 1) {
        int y = __shfl_up(inc, d);
        if (lane >= d) inc += y;
    }
    if (lane == 63) red8[wv] = inc;
    __syncthreads();
    int base0 = 0;
    #pragma unroll
    for (int q = 0; q < 4; q++) {
        int vq = red8[w * 4 + q];
        if (q < (t >> 6)) base0 += vq;
    }
    int halfTot = red8[w * 4] + red8[w * 4 + 1] + red8[w * 4 + 2] + red8[w * 4 + 3];
    int pos = base0 + (inc - c);
    #pragma unroll
    for (int k = 0; k < 8; k++) {
        if (flag[k]) {
            if (w == 0) { lsI[pos] = (short)(t0 + k); lsV[pos] = v[k]; }
            else        { leI[pos] = (short)(t0 + k); evV[pos] = v[k]; }
            pos++;
        }
    }
    if (t == 0) sN[w] = halfTot;
    __syncthreads();

    int mS = sN[0], mE = sN[1];
    float maxE = sMaxA[1];
    float maxP = sMaxA[0] * maxE;

    // ---------- totalValid ----------
    int myTot = 0;
    for (int i = tid; i < mS; i += 512) {
        int sPos = lsI[i];
        int lo2 = 0, hi2 = mE;
        while (lo2 < hi2) { int mid = (lo2 + hi2) >> 1; if (leI[mid] < sPos) lo2 = mid + 1; else hi2 = mid; }
        myTot += mE - lo2;
    }
    int totalValid = reduce512(myTot, tid, red8);

    // ---------- mode 2: fewer than K valid -> all valid pairs win ----------
    if (totalValid < KPROP) {
        if (tid == 0) scnt = 0;
        __syncthreads();
        for (int i = wv; i < mS; i += 8) {
            int sPos = lsI[i];
            for (int jb = 0; jb < mE; jb += 64) {
                int j = jb + lane;
                bool tk = (j < mE) && ((int)leI[j] >= sPos);
                unsigned long long vm = __ballot(tk);
                int cntv = __popcll(vm);
                if (cntv) {
                    int bw = 0;
                    if (lane == 0) bw = atomicAdd(&scnt, cntv);
                    bw = __shfl(bw, 0);
                    if (tk) {
                        int p2 = bw + __popcll(vm & ((1ull << lane) - 1ull));
                        if (p2 < CAP) candFlat[bc + p2] = (unsigned)((sPos << 11) | (int)leI[j]);
                    }
                }
            }
        }
        __syncthreads();
        if (tid == 0) { gMode[b] = 2; gCnt[b] = min(scnt, CAP); }
        return;
    }

    // ---------- min e-value ----------
    float mn = 3.4e38f;
    for (int k = tid; k < mE; k += 512) mn = fminf(mn, evV[k]);
    #pragma unroll
    for (int d = 32; d > 0; d >>= 1) mn = fminf(mn, (float)__shfl_down(mn, d));
    if (lane == 0) redS[wv] = mn;
    __syncthreads();
    float minV = redS[0];
    for (int w2 = 1; w2 < 8; w2++) minV = fminf(minV, redS[w2]);
    __syncthreads();
    float invW = 2047.0f / fmaxf(maxE - minV, 1e-30f);

    // ---------- counting sort of e by value bucket (desc) [verified R12-R16] ----
    for (int k = tid; k < 2048; k += 512) Pmut[k] = 0u;
    __syncthreads();
    for (int k = tid; k < mE; k += 512) {
        float kf = fminf((evV[k] - minV) * invW, 2047.0f);
        int key = (int)kf; if (key < 0) key = 0;
        atomicAdd(&Pmut[2047 - key], 1u);        // asc sk = desc value
    }
    __syncthreads();
    {   // PE[sk] = exclusive prefix; PE[2048..2050] = mE
        int c4[4], sum4 = 0;
        #pragma unroll
        for (int q = 0; q < 4; q++) { c4[q] = (int)Pmut[tid * 4 + q]; sum4 += c4[q]; }
        int tot;
        int base = scan512_excl(sum4, tid, red8, &tot);
        int run = base;
        #pragma unroll
        for (int q = 0; q < 4; q++) { PE[tid * 4 + q] = (short)run; run += c4[q]; }
        if (tid == 0) { PE[2048] = (short)tot; PE[2049] = (short)mE; PE[2050] = (short)mE; }
    }
    __syncthreads();
    for (int k = tid; k < 2048; k += 512) Pmut[k] = (unsigned)(short)PE[k];
    __syncthreads();
    for (int k = tid; k < mE; k += 512) {
        float vE = evV[k];
        float kf = fminf((vE - minV) * invW, 2047.0f);
        int key = (int)kf; if (key < 0) key = 0;
        int p2 = (int)atomicAdd(&Pmut[2047 - key], 1u);
        evVs[p2] = vE; evIs[p2] = leI[k];
    }
    __syncthreads();

    // included(tau, sv) = prefix len: all e in buckets >= bucketOf(tau/sv)-2.
    // Superset of {e: fl(sv*e) >= tau}: float err ~1e-4 bucket << 2-bucket margin.
    auto rowCount = [&](float tau, float sv) -> int {
        float x = tau / sv;
        float kf = fminf((x - minV) * invW, 2050.0f);
        int kk = (int)kf - 2;
        if (kk < -2) kk = -2;
        if (kk > 2048) kk = 2048;
        return (int)PE[2048 - kk];
    };

    // ---------- phase 1: false-position in WAVE 0 only (no block barriers) ----
    if (wv == 0) {
        float aT = 0.0f, bT = maxP;
        float Fa = (float)mS * (float)mE;    // = included(0)
        float Fb = 0.0f;
        float t40w = -1.0f;
        for (int it = 0; it < 12; it++) {
            float mid;
            float denom = Fa - Fb;
            if (denom > 1.0f) {
                mid = aT + (bT - aT) * ((Fa - 9000.0f) / denom);
                if (!(mid > aT && mid < bT)) mid = 0.5f * (aT + bT);
            } else mid = 0.5f * (aT + bT);
            int my = 0;
            for (int i = lane; i < mS; i += 64) my += rowCount(mid, lsV[i]);
            #pragma unroll
            for (int d = 32; d > 0; d >>= 1) my += __shfl_down(my, d);
            int incC = __shfl(my, 0);
            if (incC > 13000) { aT = mid; Fa = (float)incC; }
            else if (incC < 5000) { bT = mid; Fb = (float)incC; }
            else { t40w = mid; break; }
        }
        // salvage: aT's included <= 24576 -> enumeration still cheap; cert +
        // overflow-cut keep exactness. (aT may be 0: include everything.)
        if (t40w < 0.0f && Fa <= 24576.0f) t40w = aT;
        if (lane == 0) sT40 = t40w;
    }
    __syncthreads();
    float t40 = sT40;

    bool ok = false;
    bool histValid = false;
    int n = 0;
    float lo = 0.0f, bscale = 0.0f;

    if (t40 >= 0.0f) {
        // ---------- compact ACTIVE rows (C > 0) [verified R15/R16] ----------
        __shared__ int sActN;
        {
            int a4[4], na = 0;
            #pragma unroll
            for (int q = 0; q < 4; q++) {
                int i = tid * 4 + q;
                int C = (i < mS) ? rowCount(t40, lsV[i]) : 0;
                a4[q] = C; na += (C > 0);
            }
            int tot;
            int base = scan512_excl(na, tid, red8, &tot);
            int run = base;
            #pragma unroll
            for (int q = 0; q < 4; q++) {
                if (a4[q] > 0) { actI[run] = (short)(tid * 4 + q); actC[run] = (short)a4[q]; run++; }
            }
            if (tid == 0) sActN = tot;
        }
        __syncthreads();
        int actN = sActN;

        // ---------- pass A: store all valid-included + hist + exact cert ----------
        lo = t40;
        bscale = 2047.0f / fmaxf(maxP - lo, 1e-30f);
        for (int cc2 = tid; cc2 < 2048; cc2 += 512) Pmut[cc2] = 0u;
        if (tid == 0) scnt = 0;
        __syncthreads();
        int certLoc = 0;
        for (int r = wv; r < actN; r += 8) {               // wave per ACTIVE row
            int i = (int)actI[r];
            float sv = lsV[i]; int sPos = lsI[i];
            int C = (int)actC[r];
            for (int jb = 0; jb < C; jb += 64) {
                int j = jb + lane;
                bool keep = false;
                float prod = 0.0f;
                int eIdx = 0;
                if (j < C) {
                    eIdx = (int)evIs[j];
                    prod = sv * evVs[j];
                    keep = (eIdx >= sPos);
                }
                if (keep) {
                    int key = (int)((prod - lo) * bscale);
                    key = key < 0 ? 0 : (key > 2047 ? 2047 : key);
                    atomicAdd(&Pmut[key], 1u);
                    if (prod >= t40) certLoc++;
                }
                unsigned long long vm = __ballot(keep);
                int cntv = __popcll(vm);
                if (cntv) {
                    int bw = 0;
                    if (lane == 0) bw = atomicAdd(&scnt, cntv);
                    bw = __shfl(bw, 0);
                    if (keep) {
                        int p2 = bw + __popcll(vm & ((1ull << lane) - 1ull));
                        if (p2 < CAP) {
                            candFlat[bc + p2] = (unsigned)((sPos << 11) | eIdx);
                            candBits[bc + p2] = __float_as_uint(prod);
                        }
                    }
                }
            }
        }
        __syncthreads();
        n = scnt;
        __syncthreads();
        int certTot = reduce512(certLoc, tid, red8);
        // cert: >=K stored pairs have prod >= t40  ==>  V32 >= t40  ==>
        // every valid pair with bits >= V32 is included (superset) and stored.
        if (certTot >= KPROP) {
            if (n <= CAP) {
                ok = true; histValid = true;
            } else {
                // ---------- overflow: bucket-cut pass B (R13-R16-verified) ----
                dscan(Pmut, 2048, KPROP, tid, cs, &sB, &sNd);
                int bb = sB;
                if (bb >= 1) {
                    int cumBB = (KPROP - sNd) + (int)Pmut[bb];
                    if (cumBB <= CAP) {
                        if (tid == 0) scnt = 0;
                        __syncthreads();
                        for (int r = wv; r < actN; r += 8) {
                            int i = (int)actI[r];
                            float sv = lsV[i]; int sPos = lsI[i];
                            int C = (int)actC[r];
                            for (int jb = 0; jb < C; jb += 64) {
                                int j = jb + lane;
                                bool keep = false;
                                float prod = 0.0f;
                                int eIdx = 0;
                                if (j < C) {
                                    eIdx = (int)evIs[j];
                                    prod = sv * evVs[j];
                                    int key = (int)((prod - lo) * bscale);
                                    key = key < 0 ? 0 : (key > 2047 ? 2047 : key);
                                    keep = (eIdx >= sPos) && (key >= bb);
                                }
                                unsigned long long vm = __ballot(keep);
                                int cntv = __popcll(vm);
                                if (cntv) {
                                    int bw = 0;
                                    if (lane == 0) bw = atomicAdd(&scnt, cntv);
                                    bw = __shfl(bw, 0);
                                    if (keep) {
                                        int p2 = bw + __popcll(vm & ((1ull << lane) - 1ull));
                                        if (p2 < CAP) {
                                            candFlat[bc + p2] = (unsigned)((sPos << 11) | eIdx);
                                            candBits[bc + p2] = __float_as_uint(prod);
                                        }
                                    }
                                }
                            }
                        }
                        __syncthreads();
                        n = scnt;
                        __syncthreads();
                        if (n >= KPROP && n <= CAP) { ok = true; histValid = true; }
                    }
                }
            }
        }
    }

    if (!ok) {
        // ---------- exact full-scan fallback (R11-verified; pathological only) ----
        auto exactCount = [&](float tau) -> int {
            int my = 0;
            for (int i = wv; i < mS; i += 8) {
                float sv2 = lsV[i]; int sPos = lsI[i];
                for (int jb = 0; jb < mE; jb += 64) {
                    int j = jb + lane;
                    if (j < mE && (int)leI[j] >= sPos && sv2 * evV[j] >= tau) my++;
                }
            }
            return reduce512(my, tid, red8);
        };
        float a3 = 0.0f, b3 = maxP, tau3 = -1.0f;
        for (int it = 0; it < 24; it++) {
            float mid = 0.5f * (a3 + b3);
            int cnt = exactCount(mid);
            if (cnt > CAP) a3 = mid;
            else { b3 = mid; tau3 = mid; if (cnt >= KPROP) break; }
        }
        if (tau3 < 0.0f) tau3 = b3;
        if (tid == 0) scnt = 0;
        __syncthreads();
        for (int i = wv; i < mS; i += 8) {
            float sv2 = lsV[i]; int sPos = lsI[i];
            for (int jb = 0; jb < mE; jb += 64) {
                int j = jb + lane;
                float prod = (j < mE) ? sv2 * evV[j] : 0.0f;
                bool valid = (j < mE) && ((int)leI[j] >= sPos) && (prod >= tau3);
                unsigned long long vm = __ballot(valid);
                int cntv = __popcll(vm);
                if (cntv) {
                    int bw = 0;
                    if (lane == 0) bw = atomicAdd(&scnt, cntv);
                    bw = __shfl(bw, 0);
                    if (valid) {
                        int p2 = bw + __popcll(vm & ((1ull << lane) - 1ull));
                        if (p2 < CAP) {
                            candFlat[bc + p2] = (unsigned)((sPos << 11) | (int)leI[j]);
                            candBits[bc + p2] = __float_as_uint(prod);
                        }
                    }
                }
            }
        }
        __syncthreads();
        n = min(scnt, CAP);
        __syncthreads();
        if (n >= KPROP) ok = true;
    }

    if (!ok) {        // degenerate: emit what we have as mode 2
        if (tid == 0) { gMode[b] = 2; gCnt[b] = n; }
        return;
    }

    // ---------- TINY-BUCKET exact refinement (fast path) ----------
    // Pass A's value-linear hist (valid-only, uncapped) still holds; K-th is
    // in bucket bb with in-bucket rank sNd. Buckets monotone in bits (key is
    // floor of increasing linear in prod; bits monotone in prod), so all ties
    // of V32 are inside bucket bb.
    if (histValid) {
        dscan(Pmut, 2048, KPROP, tid, cs, &sB, &sNd);
        int bbT = sB, sNdT = sNd;
        if (bbT >= 0 && (int)Pmut[bbT] <= TB_CAP) {
            if (tid == 0) { tbCnt = 0; sFlag = 0; }
            __syncthreads();
            for (int k = tid; k < n; k += 512) {
                unsigned bits = candBits[bc + k];
                float prod = __uint_as_float(bits);
                int key = (int)((prod - lo) * bscale);
                key = key < 0 ? 0 : (key > 2047 ? 2047 : key);
                if (key == bbT) {
                    int pp = atomicAdd(&tbCnt, 1);
                    if (pp < TB_CAP) tb[pp] = bits;
                }
            }
            __syncthreads();
            int cntBB = tbCnt;
            if (cntBB <= TB_CAP && wv == 0) {
                unsigned v32 = 0u; int nd2v = -1;
                for (int k = lane; k < cntBB; k += 64) {
                    unsigned bk = tb[k];
                    int gt = 0, eq = 0;
                    for (int j = 0; j < cntBB; j++) {
                        unsigned bj = tb[j];
                        gt += (bj > bk) ? 1 : 0;
                        eq += (bj == bk) ? 1 : 0;
                    }
                    if (gt < sNdT && gt + eq >= sNdT) { v32 = bk; nd2v = sNdT - gt; }
                }
                unsigned long long msk = __ballot(nd2v >= 0);
                if (msk) {
                    int src = __ffsll((unsigned long long)msk) - 1;
                    v32 = __shfl(v32, src);
                    nd2v = __shfl(nd2v, src);
                    if (lane == 0) {
                        gV32[b] = v32; gNd2[b] = nd2v; gMode[b] = 1; gCnt[b] = n;
                        sFlag = 1;
                    }
                }
            }
            __syncthreads();
            if (sFlag) return;
            // else fall through to full 3-level refinement
        }
    }

    // ---------- full 3-level bit refinement (guard path; R10-R16-verified) ----
    for (int cc2 = tid; cc2 < 2048; cc2 += 512) Pmut[cc2] = 0u;
    __syncthreads();
    for (int k = tid; k < n; k += 512) atomicAdd(&Pmut[candBits[bc + k] >> 20], 1u);
    __syncthreads();
    dscan(Pmut, 2048, KPROP, tid, cs, &sB, &sNd);
    unsigned bA = (unsigned)sB;
    int ndA = sNd;
    __syncthreads();

    for (int cc2 = tid; cc2 < 1024; cc2 += 512) Pmut[cc2] = 0u;
    __syncthreads();
    for (int k = tid; k < n; k += 512) {
        unsigned bits = candBits[bc + k];
        if ((bits >> 20) == bA) atomicAdd(&Pmut[(bits >> 10) & 1023], 1u);
    }
    __syncthreads();
    dscan(Pmut, 1024, ndA, tid, cs, &sB, &sNd);
    unsigned pref20 = (bA << 10) | (unsigned)sB;
    int ndB = sNd;
    __syncthreads();

    for (int cc2 = tid; cc2 < 1024; cc2 += 512) Pmut[cc2] = 0u;
    __syncthreads();
    for (int k = tid; k < n; k += 512) {
        unsigned bits = candBits[bc + k];
        if ((bits >> 10) == pref20) atomicAdd(&Pmut[bits & 1023], 1u);
    }
    __syncthreads();
    dscan(Pmut, 1024, ndB, tid, cs, &sB, &sNd);

    if (tid == 0) {
        gV32[b] = (pref20 << 10) | (unsigned)sB;   // exact K-th score bits
        gNd2[b] = sNd;                             // ties to keep at V32
        gMode[b] = 1;
        gCnt[b]  = n;
    }
}

// K2: scatter 1.0s after K1's fill.  [verified R9-R16]
__global__ __launch_bounds__(512) void k_emit(
        const int* __restrict__ gMode, const unsigned* __restrict__ gV32,
        const int* __restrict__ gNd2, const int* __restrict__ gCnt,
        const unsigned* __restrict__ candFlat, const unsigned* __restrict__ candBits,
        float* __restrict__ out) {
    int b = blockIdx.x, tid = threadIdx.x;
    int md = gMode[b], n = gCnt[b];
    const unsigned* cf = candFlat + (size_t)b * CAP;

    if (md == 2) {
        for (int k = tid; k < n; k += 512) {
            unsigned f = cf[k];
            int s = (int)(f >> 11), e = (int)(f & 2047u);
            out[((size_t)b * NT + (e - s)) * NT + s] = 1.0f;
        }
        return;
    }

    __shared__ unsigned tie[TIE_CAP];
    __shared__ int tieCnt;
    if (tid == 0) tieCnt = 0;
    __syncthreads();

    unsigned V32 = gV32[b];
    int nd2 = gNd2[b];
    const unsigned* cb = candBits + (size_t)b * CAP;

    for (int k = tid; k < n; k += 512) {
        unsigned bits = cb[k];
        unsigned f = cf[k];
        if (bits > V32) {
            int s = (int)(f >> 11), e = (int)(f & 2047u);
            out[((size_t)b * NT + (e - s)) * NT + s] = 1.0f;
        } else if (bits == V32) {
            int pp = atomicAdd(&tieCnt, 1);
            if (pp < TIE_CAP) tie[pp] = f;
        }
    }
    __syncthreads();
    int tn = min(tieCnt, TIE_CAP);
    for (int k = tid; k < tn; k += 512) {
        unsigned f = tie[k];
        int rank = 0;
        for (int j = 0; j < tn; j++) rank += (tie[j] < f) ? 1 : 0;
        if (rank < nd2) {                 // lowest flat indices win (lax.top_k)
            int s = (int)(f >> 11), e = (int)(f & 2047u);
            out[((size_t)b * NT + (e - s)) * NT + s] = 1.0f;
        }
    }
}

extern "C" void kernel_launch(void* const* d_in, const int* in_sizes, int n_in,
                              void* d_out, int out_size, void* d_ws, size_t ws_size,
                              hipStream_t stream) {
    const float* start = (const float*)d_in[0];
    const float* end   = (const float*)d_in[1];
    // d_in[2] (actionness) unused by the reference.
    float* out = (float*)d_out;
    char* ws = (char*)d_ws;

    int*      gMode    = (int*)     (ws + 0);
    unsigned* gV32     = (unsigned*)(ws + 64);
    int*      gNd2     = (int*)     (ws + 128);
    int*      gCnt     = (int*)     (ws + 192);
    unsigned* candFlat = (unsigned*)(ws + 4096);
    unsigned* candBits = (unsigned*)(ws + 528384);

    // K1: 16 per-batch work blocks (~35 us target) + 2048 fill blocks (268 MB)
    k_main<<<NB + 2048, 512, 0, stream>>>(start, end, (float4*)out,
                                          gMode, gV32, gNd2, gCnt,
                                          candFlat, candBits);
    // K2: scatter winners/ties, strictly after the fill completes.
    k_emit<<<NB, 512, 0, stream>>>(gMode, gV32, gNd2, gCnt, candFlat, candBits, out);
}